// Round 1
// baseline (350.841 us; speedup 1.0000x reference)
//
#include <hip/hip_runtime.h>

typedef unsigned int u32;
typedef unsigned short u16;
typedef __attribute__((ext_vector_type(8))) short s8v;
typedef __attribute__((ext_vector_type(8))) __bf16 b8v;
typedef __attribute__((ext_vector_type(4))) float f4v;
typedef __attribute__((ext_vector_type(4))) u32 u32x4;

#define DEV static __device__ __forceinline__

DEV u16 f2bf(float x){ u32 u = __builtin_bit_cast(u32, x); return (u16)((u + 0x7FFFu + ((u >> 16) & 1u)) >> 16); }
DEV float bf2f(u16 u){ return __builtin_bit_cast(float, ((u32)u) << 16); }
DEV u32 packbf2(float a, float b){ return (u32)f2bf(a) | (((u32)f2bf(b)) << 16); }

DEV f4v mfma16(s8v a, s8v b, f4v c){
  return __builtin_amdgcn_mfma_f32_16x16x32_bf16(__builtin_bit_cast(b8v, a), __builtin_bit_cast(b8v, b), c, 0, 0, 0);
}

DEV void gl_lds16(const void* g, void* l){
  __builtin_amdgcn_global_load_lds((const __attribute__((address_space(1))) u32*)g,
                                   (__attribute__((address_space(3))) u32*)l, 16, 0, 0);
}

// ---------------- prep: X fp32 -> bf16 ----------------
__global__ __launch_bounds__(256) void k_prepx(const float* __restrict__ x, u16* __restrict__ xb, int n){
  int i = (blockIdx.x * 256 + threadIdx.x) * 8;
  if (i >= n) return;
  float4 a = *(const float4*)(x + i);
  float4 b = *(const float4*)(x + i + 4);
  u32x4 o;
  o.x = packbf2(a.x, a.y); o.y = packbf2(a.z, a.w);
  o.z = packbf2(b.x, b.y); o.w = packbf2(b.z, b.w);
  *(u32x4*)(xb + i) = o;
}

// ---------------- prep: transpose fp32 [K][N] -> bf16 [N][K] (ldd) ----------------
__global__ __launch_bounds__(256) void k_transpose(const float* __restrict__ src, u16* __restrict__ dst,
                                                   int K, int N, int ldd){
  __shared__ float t[32][33];
  int nt = N >> 5;
  int k0 = (blockIdx.x / nt) << 5, n0 = (blockIdx.x % nt) << 5;
  int col = threadIdx.x & 31, rw = threadIdx.x >> 5;
  #pragma unroll
  for (int i = 0; i < 4; i++){ int r = rw + i * 8; t[r][col] = src[(k0 + r) * N + n0 + col]; }
  __syncthreads();
  #pragma unroll
  for (int i = 0; i < 4; i++){ int r = rw + i * 8; dst[(n0 + r) * ldd + k0 + col] = f2bf(t[col][r]); }
}

// ---------------- GEMM: C[M,N] = A[M,K] * Bt[N,K]^T, bf16 in, bf16 or f32 out ----------------
template<int OUTF32>
__global__ __launch_bounds__(256) void k_gemm(const u16* __restrict__ A, const u16* __restrict__ Bt,
                                              void* __restrict__ Cv, int M, int N, int K){
  __shared__ u16 sA[128 * 64];
  __shared__ u16 sB[128 * 64];
  int tid = threadIdx.x, w = tid >> 6, lane = tid & 63, g = lane >> 4, c = lane & 15;
  int n0 = blockIdx.x << 7, m0 = blockIdx.y << 7;
  int wr = w >> 1, wc = w & 1;
  f4v acc[4][4] = {};
  int srow = lane >> 3;                 // 0..7
  int sslot = (lane & 7) ^ srow;        // source-side XOR swizzle
  const u16* Abase = A + (m0 + srow) * K + sslot * 8;
  const u16* Bbase = Bt + (n0 + srow) * K + sslot * 8;
  #pragma unroll 1
  for (int kt = 0; kt < K; kt += 64){
    #pragma unroll
    for (int ii = 0; ii < 4; ii++){
      int i = w * 4 + ii;
      gl_lds16(Abase + i * 8 * K + kt, sA + i * 512);
      gl_lds16(Bbase + i * 8 * K + kt, sB + i * 512);
    }
    __syncthreads();
    #pragma unroll
    for (int kk = 0; kk < 2; kk++){
      s8v af[4], bfr[4];
      #pragma unroll
      for (int mi = 0; mi < 4; mi++){
        int r = (wr << 6) + (mi << 4) + c;
        int slot = ((kk << 2) + g) ^ (r & 7);
        af[mi] = *(const s8v*)(sA + r * 64 + slot * 8);
      }
      #pragma unroll
      for (int ni = 0; ni < 4; ni++){
        int r = (wc << 6) + (ni << 4) + c;
        int slot = ((kk << 2) + g) ^ (r & 7);
        bfr[ni] = *(const s8v*)(sB + r * 64 + slot * 8);
      }
      #pragma unroll
      for (int mi = 0; mi < 4; mi++)
        #pragma unroll
        for (int ni = 0; ni < 4; ni++)
          acc[mi][ni] = mfma16(af[mi], bfr[ni], acc[mi][ni]);
    }
    __syncthreads();
  }
  #pragma unroll
  for (int mi = 0; mi < 4; mi++){
    #pragma unroll
    for (int ni = 0; ni < 4; ni++){
      #pragma unroll
      for (int r = 0; r < 4; r++){
        int m = m0 + (wr << 6) + (mi << 4) + (g << 2) + r;
        int n = n0 + (wc << 6) + (ni << 4) + c;
        if (OUTF32) ((float*)Cv)[m * N + n] = acc[mi][ni][r];
        else        ((u16*)Cv)[m * N + n] = f2bf(acc[mi][ni][r]);
      }
    }
  }
}

// ---------------- RMSNorm + RoPE for Q (heads 0..15) and K (16..23) ----------------
// Y: bf16 [8192][2304]; writes Qp [4][16][2048][104], Kp [4][8][2048][104] (dims 72..103 zero)
__global__ __launch_bounds__(192) void k_normrope(const u16* __restrict__ Y, const float* __restrict__ cosp,
      const float* __restrict__ sinp, const float* __restrict__ qnw, const float* __restrict__ knw,
      u16* __restrict__ Qp, u16* __restrict__ Kp){
  __shared__ float ly[1728];
  int token = blockIdx.x;
  int t = threadIdx.x, head = t >> 3, j = t & 7;
  int base = head * 72 + j * 9;
  const u16* yr = Y + token * 2304;
  float x[9]; float ss = 0.f;
  #pragma unroll
  for (int i = 0; i < 9; i++){ x[i] = bf2f(yr[base + i]); ss += x[i] * x[i]; }
  ss += __shfl_xor(ss, 1); ss += __shfl_xor(ss, 2); ss += __shfl_xor(ss, 4);
  float inv = rsqrtf(ss * (1.f / 72.f) + 1e-6f);
  const float* wn = (head < 16) ? qnw : knw;
  #pragma unroll
  for (int i = 0; i < 9; i++){ int d = j * 9 + i; ly[base + i] = x[i] * inv * (1.f + wn[d]); }
  __syncthreads();
  const float* cs = cosp + token * 72;
  const float* sn = sinp + token * 72;
  float o[9];
  #pragma unroll
  for (int i = 0; i < 9; i++){
    int d = j * 9 + i;
    int dm = (d >= 36) ? d - 36 : d;
    float rot = (dm < 18) ? -ly[head * 72 + d + 18] : ly[head * 72 + d - 18];
    o[i] = ly[base + i] * cs[d] + rot * sn[d];
  }
  int b = token >> 11, s = token & 2047;
  u16* dst;
  if (head < 16) dst = Qp + (((b << 4) + head) * 2048 + s) * 104;
  else           dst = Kp + (((b << 3) + (head - 16)) * 2048 + s) * 104;
  #pragma unroll
  for (int i = 0; i < 9; i++) dst[j * 9 + i] = f2bf(o[i]);
  #pragma unroll
  for (int p2 = 0; p2 < 4; p2++) dst[72 + j * 4 + p2] = 0;
}

// ---------------- V: RMSNorm (no scale) + transpose -> Vt [4][8][72][2048] ----------------
__global__ __launch_bounds__(256) void k_vtrans(const u16* __restrict__ Y, u16* __restrict__ Vt){
  __shared__ float lv[72][33];
  int st = blockIdx.x, bk = blockIdx.y;       // st: s-tile of 32; bk = b*8+kvh
  int b = bk >> 3, kvh = bk & 7;
  int t = threadIdx.x, tl = t >> 3, j = t & 7;
  int token = (b << 11) + (st << 5) + tl;
  const u16* yr = Y + token * 2304 + 1728 + kvh * 72 + j * 9;
  float x[9]; float ss = 0.f;
  #pragma unroll
  for (int i = 0; i < 9; i++){ x[i] = bf2f(yr[i]); ss += x[i] * x[i]; }
  ss += __shfl_xor(ss, 1); ss += __shfl_xor(ss, 2); ss += __shfl_xor(ss, 4);
  float inv = rsqrtf(ss * (1.f / 72.f) + 1e-6f);
  #pragma unroll
  for (int i = 0; i < 9; i++) lv[j * 9 + i][tl] = x[i] * inv;
  __syncthreads();
  u16* vb = Vt + bk * 72 * 2048 + (st << 5);
  for (int e = t; e < 72 * 32; e += 256){
    int r = e >> 5, cl = e & 31;
    vb[r * 2048 + cl] = f2bf(lv[r][cl]);
  }
}

// ---------------- Flash attention ----------------
// grid (32 qtiles, 64 b*h). 4 waves x 16 q-rows. KT=64. Dpad=104 (96 used by MFMA, zeros past 71).
__global__ __launch_bounds__(256) void k_attn(const u16* __restrict__ Qp, const u16* __restrict__ Kp,
                                              const u16* __restrict__ Vt, u16* __restrict__ O){
  __shared__ u16 sK[64 * 104];     // 13312 B
  __shared__ u16 sV[80 * 72];      // 11520 B (rows 72..79 zeroed; d-pad for M-tile 4)
  __shared__ u16 sP[4][16 * 72];   // 9216 B, per-wave
  int tid = threadIdx.x, w = tid >> 6, lane = tid & 63, g = lane >> 4, c = lane & 15;
  int qt = blockIdx.x, bh = blockIdx.y, b = bh >> 4, h = bh & 15, kv = h >> 1;
  int qrow = (qt << 6) + (w << 4) + c;
  const u16* qb = Qp + ((((b << 4) + h) << 11) + qrow) * 104 + g * 8;
  s8v qf[3];
  #pragma unroll
  for (int kk = 0; kk < 3; kk++) qf[kk] = *(const s8v*)(qb + kk * 32);
  f4v ao[5] = {};
  float mv = -3.0e38f, ls = 0.f;
  const u16* kb = Kp + (((b << 3) + kv) << 11) * 104;
  const u16* vbase = Vt + ((b << 3) + kv) * 72 * 2048;
  u16* myP = &sP[w][0];
  for (int e = tid; e < 8 * 72; e += 256) sV[72 * 72 + e] = 0;  // zero d-pad rows
  #pragma unroll 1
  for (int kt = 0; kt < 2048; kt += 64){
    const char* ks = (const char*)(kb + kt * 104);
    for (int i = w; i < 13; i += 4)
      gl_lds16(ks + i * 1024 + lane * 16, (char*)sK + i * 1024);
    for (int e = tid; e < 576; e += 256){
      int r = e >> 3, off = e & 7;
      *(s8v*)(sV + r * 72 + off * 8) = *(const s8v*)(vbase + r * 2048 + kt + off * 8);
    }
    __syncthreads();
    f4v sc[4] = {};
    #pragma unroll
    for (int mt = 0; mt < 4; mt++){
      #pragma unroll
      for (int kk = 0; kk < 3; kk++){
        s8v kf = *(const s8v*)(sK + (mt * 16 + c) * 104 + kk * 32 + g * 8);
        sc[mt] = mfma16(kf, qf[kk], sc[mt]);
      }
    }
    float tm = -3.0e38f;
    #pragma unroll
    for (int mt = 0; mt < 4; mt++)
      #pragma unroll
      for (int r = 0; r < 4; r++) tm = fmaxf(tm, sc[mt][r]);
    tm = fmaxf(tm, __shfl_xor(tm, 16));
    tm = fmaxf(tm, __shfl_xor(tm, 32));
    float mn = fmaxf(mv, tm);
    float scl = __expf(mv - mn);
    float p[16]; float ts = 0.f;
    #pragma unroll
    for (int mt = 0; mt < 4; mt++)
      #pragma unroll
      for (int r = 0; r < 4; r++){ float pv = __expf(sc[mt][r] - mn); p[mt * 4 + r] = pv; ts += pv; }
    ts += __shfl_xor(ts, 16); ts += __shfl_xor(ts, 32);
    ls = ls * scl + ts; mv = mn;
    #pragma unroll
    for (int db = 0; db < 5; db++)
      #pragma unroll
      for (int r = 0; r < 4; r++) ao[db][r] *= scl;
    #pragma unroll
    for (int mt = 0; mt < 4; mt++){
      *(u32*)(myP + c * 72 + mt * 16 + g * 4)     = packbf2(p[mt * 4 + 0], p[mt * 4 + 1]);
      *(u32*)(myP + c * 72 + mt * 16 + g * 4 + 2) = packbf2(p[mt * 4 + 2], p[mt * 4 + 3]);
    }
    #pragma unroll
    for (int k2 = 0; k2 < 2; k2++){
      s8v pf = *(const s8v*)(myP + c * 72 + k2 * 32 + g * 8);
      #pragma unroll
      for (int db = 0; db < 5; db++){
        s8v vf = *(const s8v*)(sV + (db * 16 + c) * 72 + k2 * 32 + g * 8);
        ao[db] = mfma16(vf, pf, ao[db]);
      }
    }
    __syncthreads();
  }
  float inv = 1.f / ls;
  u16* ob = O + ((((b << 11) + qrow) << 4) + h) * 72;
  #pragma unroll
  for (int db = 0; db < 5; db++){
    #pragma unroll
    for (int pr = 0; pr < 2; pr++){
      int dd = db * 16 + g * 4 + pr * 2;
      if (dd < 72)
        *(u32*)(ob + dd) = packbf2(ao[db][pr * 2] * inv, ao[db][pr * 2 + 1] * inv);
    }
  }
}

// ---------------- launch ----------------
extern "C" void kernel_launch(void* const* d_in, const int* in_sizes, int n_in,
                              void* d_out, int out_size, void* d_ws, size_t ws_size,
                              hipStream_t stream){
  (void)in_sizes; (void)n_in; (void)out_size; (void)ws_size;
  const float* hs   = (const float*)d_in[0];
  const float* cosp = (const float*)d_in[1];
  const float* sinp = (const float*)d_in[2];
  const float* Wq   = (const float*)d_in[5];
  const float* Wk   = (const float*)d_in[6];
  const float* Wv   = (const float*)d_in[7];
  const float* Wo   = (const float*)d_in[8];
  const float* qnw  = (const float*)d_in[9];
  const float* knw  = (const float*)d_in[10];
  char* ws = (char*)d_ws;
  u16* Xb    = (u16*)(ws);                    // 18,874,368 B (reused as O after gemm1)
  u16* WtQKV = (u16*)(ws + 18874368);         //  5,308,416 B
  u16* Wot   = (u16*)(ws + 24182784);         //  2,654,208 B
  u16* Y     = (u16*)(ws + 26836992);         // 37,748,736 B
  u16* Qp    = (u16*)(ws + 64585728);         // 27,262,976 B
  u16* Kp    = (u16*)(ws + 91848704);         // 13,631,488 B
  u16* Vt    = (u16*)(ws + 105480192);        //  9,437,184 B  (total 114,917,376)
  u16* O     = Xb;

  k_prepx<<<4608, 256, 0, stream>>>(hs, Xb, 8192 * 1152);
  k_transpose<<<36 * 36, 256, 0, stream>>>(Wq, WtQKV, 1152, 1152, 1152);
  k_transpose<<<36 * 18, 256, 0, stream>>>(Wk, WtQKV + 1152 * 1152, 1152, 576, 1152);
  k_transpose<<<36 * 18, 256, 0, stream>>>(Wv, WtQKV + 1728 * 1152, 1152, 576, 1152);
  k_transpose<<<36 * 36, 256, 0, stream>>>(Wo, Wot, 1152, 1152, 1152);
  k_gemm<0><<<dim3(18, 64), 256, 0, stream>>>(Xb, WtQKV, Y, 8192, 2304, 1152);
  k_normrope<<<8192, 192, 0, stream>>>(Y, cosp, sinp, qnw, knw, Qp, Kp);
  k_vtrans<<<dim3(64, 32), 256, 0, stream>>>(Y, Vt);
  k_attn<<<dim3(32, 64), 256, 0, stream>>>(Qp, Kp, Vt, O);
  k_gemm<1><<<dim3(9, 64), 256, 0, stream>>>(O, Wot, (float*)d_out, 8192, 1152, 1152);
}

// Round 2
// 347.252 us; speedup vs baseline: 1.0103x; 1.0103x over previous
//
#include <hip/hip_runtime.h>

typedef unsigned int u32;
typedef unsigned short u16;
typedef __attribute__((ext_vector_type(8))) short s8v;
typedef __attribute__((ext_vector_type(8))) __bf16 b8v;
typedef __attribute__((ext_vector_type(4))) float f4v;
typedef __attribute__((ext_vector_type(4))) u32 u32x4;
typedef __attribute__((ext_vector_type(2))) u32 u32x2;

#define DEV static __device__ __forceinline__

DEV u32 cvtpk(float a, float b){ u32 r; asm("v_cvt_pk_bf16_f32 %0, %1, %2" : "=v"(r) : "v"(a), "v"(b)); return r; }
DEV u16 f2bf(float x){ return (u16)(cvtpk(x, x) & 0xffffu); }
DEV float bf2f(u16 u){ return __builtin_bit_cast(float, ((u32)u) << 16); }

DEV f4v mfma16(s8v a, s8v b, f4v c){
  return __builtin_amdgcn_mfma_f32_16x16x32_bf16(__builtin_bit_cast(b8v, a), __builtin_bit_cast(b8v, b), c, 0, 0, 0);
}

DEV void gl_lds16(const void* g, void* l){
  __builtin_amdgcn_global_load_lds((const __attribute__((address_space(1))) u32*)g,
                                   (__attribute__((address_space(3))) u32*)l, 16, 0, 0);
}

// ---------------- prep: X fp32 -> bf16 ----------------
__global__ __launch_bounds__(256) void k_prepx(const float* __restrict__ x, u16* __restrict__ xb, int n){
  int i = (blockIdx.x * 256 + threadIdx.x) * 8;
  if (i >= n) return;
  float4 a = *(const float4*)(x + i);
  float4 b = *(const float4*)(x + i + 4);
  u32x4 o;
  o.x = cvtpk(a.x, a.y); o.y = cvtpk(a.z, a.w);
  o.z = cvtpk(b.x, b.y); o.w = cvtpk(b.z, b.w);
  *(u32x4*)(xb + i) = o;
}

// ---------------- prep: transpose fp32 [K][N] -> bf16 [N][K] (ldd) ----------------
__global__ __launch_bounds__(256) void k_transpose(const float* __restrict__ src, u16* __restrict__ dst,
                                                   int K, int N, int ldd){
  __shared__ float t[32][33];
  int nt = N >> 5;
  int k0 = (blockIdx.x / nt) << 5, n0 = (blockIdx.x % nt) << 5;
  int col = threadIdx.x & 31, rw = threadIdx.x >> 5;
  #pragma unroll
  for (int i = 0; i < 4; i++){ int r = rw + i * 8; t[r][col] = src[(k0 + r) * N + n0 + col]; }
  __syncthreads();
  #pragma unroll
  for (int i = 0; i < 4; i++){ int r = rw + i * 8; dst[(n0 + r) * ldd + k0 + col] = f2bf(t[col][r]); }
}

// ---------------- GEMM: C[M,N] = A[M,K] * Bt[N,K]^T, bf16 in, bf16 or f32 out ----------------
template<int OUTF32>
__global__ __launch_bounds__(256) void k_gemm(const u16* __restrict__ A, const u16* __restrict__ Bt,
                                              void* __restrict__ Cv, int M, int N, int K){
  __shared__ u16 sA[128 * 64];
  __shared__ u16 sB[128 * 64];
  int tid = threadIdx.x, w = tid >> 6, lane = tid & 63, g = lane >> 4, c = lane & 15;
  int n0 = blockIdx.x << 7, m0 = blockIdx.y << 7;
  int wr = w >> 1, wc = w & 1;
  f4v acc[4][4] = {};
  int srow = lane >> 3;                 // 0..7
  int sslot = (lane & 7) ^ srow;        // source-side XOR swizzle
  const u16* Abase = A + (m0 + srow) * K + sslot * 8;
  const u16* Bbase = Bt + (n0 + srow) * K + sslot * 8;
  #pragma unroll 1
  for (int kt = 0; kt < K; kt += 64){
    #pragma unroll
    for (int ii = 0; ii < 4; ii++){
      int i = w * 4 + ii;
      gl_lds16(Abase + i * 8 * K + kt, sA + i * 512);
      gl_lds16(Bbase + i * 8 * K + kt, sB + i * 512);
    }
    __syncthreads();
    #pragma unroll
    for (int kk = 0; kk < 2; kk++){
      s8v af[4], bfr[4];
      #pragma unroll
      for (int mi = 0; mi < 4; mi++){
        int r = (wr << 6) + (mi << 4) + c;
        int slot = ((kk << 2) + g) ^ (r & 7);
        af[mi] = *(const s8v*)(sA + r * 64 + slot * 8);
      }
      #pragma unroll
      for (int ni = 0; ni < 4; ni++){
        int r = (wc << 6) + (ni << 4) + c;
        int slot = ((kk << 2) + g) ^ (r & 7);
        bfr[ni] = *(const s8v*)(sB + r * 64 + slot * 8);
      }
      #pragma unroll
      for (int mi = 0; mi < 4; mi++)
        #pragma unroll
        for (int ni = 0; ni < 4; ni++)
          acc[mi][ni] = mfma16(af[mi], bfr[ni], acc[mi][ni]);
    }
    __syncthreads();
  }
  #pragma unroll
  for (int mi = 0; mi < 4; mi++){
    #pragma unroll
    for (int ni = 0; ni < 4; ni++){
      #pragma unroll
      for (int r = 0; r < 4; r++){
        int m = m0 + (wr << 6) + (mi << 4) + (g << 2) + r;
        int n = n0 + (wc << 6) + (ni << 4) + c;
        if (OUTF32) ((float*)Cv)[m * N + n] = acc[mi][ni][r];
        else        ((u16*)Cv)[m * N + n] = f2bf(acc[mi][ni][r]);
      }
    }
  }
}

// ---------------- RMSNorm + RoPE for Q (heads 0..15, scaled by log2e) and K (16..23) ----------------
__global__ __launch_bounds__(192) void k_normrope(const u16* __restrict__ Y, const float* __restrict__ cosp,
      const float* __restrict__ sinp, const float* __restrict__ qnw, const float* __restrict__ knw,
      u16* __restrict__ Qp, u16* __restrict__ Kp){
  __shared__ float ly[1728];
  int token = blockIdx.x;
  int t = threadIdx.x, head = t >> 3, j = t & 7;
  int base = head * 72 + j * 9;
  const u16* yr = Y + token * 2304;
  float x[9]; float ss = 0.f;
  #pragma unroll
  for (int i = 0; i < 9; i++){ x[i] = bf2f(yr[base + i]); ss += x[i] * x[i]; }
  ss += __shfl_xor(ss, 1); ss += __shfl_xor(ss, 2); ss += __shfl_xor(ss, 4);
  float inv = rsqrtf(ss * (1.f / 72.f) + 1e-6f);
  const float* wn = (head < 16) ? qnw : knw;
  #pragma unroll
  for (int i = 0; i < 9; i++){ int d = j * 9 + i; ly[base + i] = x[i] * inv * (1.f + wn[d]); }
  __syncthreads();
  const float* cs = cosp + token * 72;
  const float* sn = sinp + token * 72;
  float scale = (head < 16) ? 1.4426950408889634f : 1.0f;   // fold log2(e) into Q
  float o[9];
  #pragma unroll
  for (int i = 0; i < 9; i++){
    int d = j * 9 + i;
    int dm = (d >= 36) ? d - 36 : d;
    float rot = (dm < 18) ? -ly[head * 72 + d + 18] : ly[head * 72 + d - 18];
    o[i] = (ly[base + i] * cs[d] + rot * sn[d]) * scale;
  }
  int b = token >> 11, s = token & 2047;
  u16* dst;
  if (head < 16) dst = Qp + (((b << 4) + head) * 2048 + s) * 104;
  else           dst = Kp + (((b << 3) + (head - 16)) * 2048 + s) * 104;
  #pragma unroll
  for (int i = 0; i < 9; i++) dst[j * 9 + i] = f2bf(o[i]);
  #pragma unroll
  for (int p2 = 0; p2 < 4; p2++) dst[72 + j * 4 + p2] = 0;
}

// ---------------- V: RMSNorm (no scale) + transpose -> Vt [4][8][72][2048] ----------------
__global__ __launch_bounds__(256) void k_vtrans(const u16* __restrict__ Y, u16* __restrict__ Vt){
  __shared__ float lv[72][33];
  int st = blockIdx.x, bk = blockIdx.y;
  int b = bk >> 3, kvh = bk & 7;
  int t = threadIdx.x, tl = t >> 3, j = t & 7;
  int token = (b << 11) + (st << 5) + tl;
  const u16* yr = Y + token * 2304 + 1728 + kvh * 72 + j * 9;
  float x[9]; float ss = 0.f;
  #pragma unroll
  for (int i = 0; i < 9; i++){ x[i] = bf2f(yr[i]); ss += x[i] * x[i]; }
  ss += __shfl_xor(ss, 1); ss += __shfl_xor(ss, 2); ss += __shfl_xor(ss, 4);
  float inv = rsqrtf(ss * (1.f / 72.f) + 1e-6f);
  #pragma unroll
  for (int i = 0; i < 9; i++) lv[j * 9 + i][tl] = x[i] * inv;
  __syncthreads();
  u16* vb = Vt + bk * 72 * 2048 + (st << 5);
  for (int e = t; e < 72 * 32; e += 256){
    int r = e >> 5, cl = e & 31;
    vb[r * 2048 + cl] = f2bf(lv[r][cl]);
  }
}

// ---------------- Flash attention ----------------
// grid (16 qtiles of 128, 64 b*h). 8 waves x 16 q-rows. KT=64. exp2-domain softmax.
#define SVS 88   // sV row stride (u16): 44 dwords -> <=2-way banks, 16B aligned
#define SPS 88   // sP row stride
__global__ __launch_bounds__(512) void k_attn(const u16* __restrict__ Qp, const u16* __restrict__ Kp,
                                              const u16* __restrict__ Vt, u16* __restrict__ O){
  __shared__ u16 sK[64 * 104];       // 13312 B, linear for global_load_lds
  __shared__ u16 sV[80 * SVS];       // 14080 B (rows 72..79 never written; outputs discarded)
  __shared__ u16 sP[8][16 * SPS];    // 22528 B, per-wave
  int tid = threadIdx.x, w = tid >> 6, lane = tid & 63, g = lane >> 4, c = lane & 15;
  int qt = blockIdx.x, bh = blockIdx.y, b = bh >> 4, h = bh & 15, kv = h >> 1;
  int qrow = (qt << 7) + (w << 4) + c;
  const u16* qb = Qp + ((((b << 4) + h) << 11) + qrow) * 104 + g * 8;
  s8v qf[3];
  #pragma unroll
  for (int kk = 0; kk < 3; kk++) qf[kk] = *(const s8v*)(qb + kk * 32);
  f4v ao[5] = {};
  float mv = -3.0e38f, lsp = 0.f;
  const u16* kb = Kp + (((b << 3) + kv) << 11) * 104;
  const u16* vbase = Vt + ((b << 3) + kv) * 72 * 2048;
  u16* myP = &sP[w][0];
  u16* pw = myP + c * SPS + g * 4;
  const u16* pr = myP + c * SPS + g * 8;
  #pragma unroll 1
  for (int kt = 0; kt < 2048; kt += 64){
    const char* ks = (const char*)(kb + kt * 104);
    for (int i = w; i < 13; i += 8)
      gl_lds16(ks + i * 1024 + lane * 16, (char*)sK + i * 1024);
    for (int e = tid; e < 576; e += 512){
      int r = e >> 3, off = e & 7;
      *(s8v*)(sV + r * SVS + off * 8) = *(const s8v*)(vbase + r * 2048 + kt + off * 8);
    }
    __syncthreads();
    f4v sc[4] = {};
    #pragma unroll
    for (int mt = 0; mt < 4; mt++){
      #pragma unroll
      for (int kk = 0; kk < 3; kk++){
        s8v kf = *(const s8v*)(sK + (mt * 16 + c) * 104 + kk * 32 + g * 8);
        sc[mt] = mfma16(kf, qf[kk], sc[mt]);
      }
    }
    float tm = -3.0e38f;
    #pragma unroll
    for (int mt = 0; mt < 4; mt++){
      float a0 = fmaxf(sc[mt][0], sc[mt][1]), a1 = fmaxf(sc[mt][2], sc[mt][3]);
      tm = fmaxf(tm, fmaxf(a0, a1));
    }
    tm = fmaxf(tm, __shfl_xor(tm, 16));
    tm = fmaxf(tm, __shfl_xor(tm, 32));
    if (!__all(tm <= mv + 8.f)){            // defer-rescale: P bounded by 2^8
      float mn = fmaxf(mv, tm);
      float scl = exp2f(mv - mn);
      lsp *= scl;
      #pragma unroll
      for (int db = 0; db < 5; db++)
        #pragma unroll
        for (int r = 0; r < 4; r++) ao[db][r] *= scl;
      mv = mn;
    }
    float ts = 0.f;
    #pragma unroll
    for (int mt = 0; mt < 4; mt++){
      float p0 = exp2f(sc[mt][0] - mv), p1 = exp2f(sc[mt][1] - mv);
      float p2 = exp2f(sc[mt][2] - mv), p3 = exp2f(sc[mt][3] - mv);
      ts += (p0 + p1) + (p2 + p3);
      u32x2 pk; pk.x = cvtpk(p0, p1); pk.y = cvtpk(p2, p3);
      *(u32x2*)(pw + mt * 16) = pk;
    }
    lsp += ts;
    #pragma unroll
    for (int k2 = 0; k2 < 2; k2++){
      s8v pf = *(const s8v*)(pr + k2 * 32);
      #pragma unroll
      for (int db = 0; db < 5; db++){
        s8v vf = *(const s8v*)(sV + (db * 16 + c) * SVS + k2 * 32 + g * 8);
        ao[db] = mfma16(vf, pf, ao[db]);
      }
    }
    __syncthreads();
  }
  float ls = lsp;
  ls += __shfl_xor(ls, 16);
  ls += __shfl_xor(ls, 32);
  float inv = 1.f / ls;
  u16* ob = O + ((((b << 11) + qrow) << 4) + h) * 72;
  #pragma unroll
  for (int db = 0; db < 5; db++){
    #pragma unroll
    for (int pr2 = 0; pr2 < 2; pr2++){
      int dd = db * 16 + g * 4 + pr2 * 2;
      if (dd < 72)
        *(u32*)(ob + dd) = cvtpk(ao[db][pr2 * 2] * inv, ao[db][pr2 * 2 + 1] * inv);
    }
  }
}

// ---------------- launch ----------------
extern "C" void kernel_launch(void* const* d_in, const int* in_sizes, int n_in,
                              void* d_out, int out_size, void* d_ws, size_t ws_size,
                              hipStream_t stream){
  (void)in_sizes; (void)n_in; (void)out_size; (void)ws_size;
  const float* hs   = (const float*)d_in[0];
  const float* cosp = (const float*)d_in[1];
  const float* sinp = (const float*)d_in[2];
  const float* Wq   = (const float*)d_in[5];
  const float* Wk   = (const float*)d_in[6];
  const float* Wv   = (const float*)d_in[7];
  const float* Wo   = (const float*)d_in[8];
  const float* qnw  = (const float*)d_in[9];
  const float* knw  = (const float*)d_in[10];
  char* ws = (char*)d_ws;
  u16* Xb    = (u16*)(ws);                    // 18,874,368 B (reused as O after gemm1)
  u16* WtQKV = (u16*)(ws + 18874368);         //  5,308,416 B
  u16* Wot   = (u16*)(ws + 24182784);         //  2,654,208 B
  u16* Y     = (u16*)(ws + 26836992);         // 37,748,736 B
  u16* Qp    = (u16*)(ws + 64585728);         // 27,262,976 B
  u16* Kp    = (u16*)(ws + 91848704);         // 13,631,488 B
  u16* Vt    = (u16*)(ws + 105480192);        //  9,437,184 B  (total 114,917,376)
  u16* O     = Xb;

  k_prepx<<<4608, 256, 0, stream>>>(hs, Xb, 8192 * 1152);
  k_transpose<<<36 * 36, 256, 0, stream>>>(Wq, WtQKV, 1152, 1152, 1152);
  k_transpose<<<36 * 18, 256, 0, stream>>>(Wk, WtQKV + 1152 * 1152, 1152, 576, 1152);
  k_transpose<<<36 * 18, 256, 0, stream>>>(Wv, WtQKV + 1728 * 1152, 1152, 576, 1152);
  k_transpose<<<36 * 36, 256, 0, stream>>>(Wo, Wot, 1152, 1152, 1152);
  k_gemm<0><<<dim3(18, 64), 256, 0, stream>>>(Xb, WtQKV, Y, 8192, 2304, 1152);
  k_normrope<<<8192, 192, 0, stream>>>(Y, cosp, sinp, qnw, knw, Qp, Kp);
  k_vtrans<<<dim3(64, 32), 256, 0, stream>>>(Y, Vt);
  k_attn<<<dim3(16, 64), 512, 0, stream>>>(Qp, Kp, Vt, O);
  k_gemm<1><<<dim3(9, 64), 256, 0, stream>>>(O, Wot, (float*)d_out, 8192, 1152, 1152);
}

// Round 3
// 328.061 us; speedup vs baseline: 1.0694x; 1.0585x over previous
//
#include <hip/hip_runtime.h>

typedef unsigned int u32;
typedef unsigned short u16;
typedef __attribute__((ext_vector_type(8))) short s8v;
typedef __attribute__((ext_vector_type(8))) __bf16 b8v;
typedef __attribute__((ext_vector_type(4))) float f4v;
typedef __attribute__((ext_vector_type(4))) u32 u32x4;
typedef __attribute__((ext_vector_type(2))) u32 u32x2;

#define DEV static __device__ __forceinline__

DEV u32 cvtpk(float a, float b){ u32 r; asm("v_cvt_pk_bf16_f32 %0, %1, %2" : "=v"(r) : "v"(a), "v"(b)); return r; }
DEV u16 f2bf(float x){ return (u16)(cvtpk(x, x) & 0xffffu); }
DEV float bf2f(u16 u){ return __builtin_bit_cast(float, ((u32)u) << 16); }

DEV f4v mfma16(s8v a, s8v b, f4v c){
  return __builtin_amdgcn_mfma_f32_16x16x32_bf16(__builtin_bit_cast(b8v, a), __builtin_bit_cast(b8v, b), c, 0, 0, 0);
}

DEV void gl_lds16(const void* g, void* l){
  __builtin_amdgcn_global_load_lds((const __attribute__((address_space(1))) u32*)g,
                                   (__attribute__((address_space(3))) u32*)l, 16, 0, 0);
}

// ---------------- prep: X fp32 -> bf16 ----------------
__global__ __launch_bounds__(256) void k_prepx(const float* __restrict__ x, u16* __restrict__ xb, int n){
  int i = (blockIdx.x * 256 + threadIdx.x) * 8;
  if (i >= n) return;
  float4 a = *(const float4*)(x + i);
  float4 b = *(const float4*)(x + i + 4);
  u32x4 o;
  o.x = cvtpk(a.x, a.y); o.y = cvtpk(a.z, a.w);
  o.z = cvtpk(b.x, b.y); o.w = cvtpk(b.z, b.w);
  *(u32x4*)(xb + i) = o;
}

// ---------------- prep: transpose fp32 [K][N] -> bf16 [N][K] (ldd) ----------------
__global__ __launch_bounds__(256) void k_transpose(const float* __restrict__ src, u16* __restrict__ dst,
                                                   int K, int N, int ldd){
  __shared__ float t[32][33];
  int nt = N >> 5;
  int k0 = (blockIdx.x / nt) << 5, n0 = (blockIdx.x % nt) << 5;
  int col = threadIdx.x & 31, rw = threadIdx.x >> 5;
  #pragma unroll
  for (int i = 0; i < 4; i++){ int r = rw + i * 8; t[r][col] = src[(k0 + r) * N + n0 + col]; }
  __syncthreads();
  #pragma unroll
  for (int i = 0; i < 4; i++){ int r = rw + i * 8; dst[(n0 + r) * ldd + k0 + col] = f2bf(t[col][r]); }
}

// ---------------- GEMM: C[M,N] = A[M,K] * Bt[N,K]^T, bf16 in, bf16 or f32 out ----------------
template<int OUTF32>
__global__ __launch_bounds__(256) void k_gemm(const u16* __restrict__ A, const u16* __restrict__ Bt,
                                              void* __restrict__ Cv, int M, int N, int K){
  __shared__ u16 sA[128 * 64];
  __shared__ u16 sB[128 * 64];
  int tid = threadIdx.x, w = tid >> 6, lane = tid & 63, g = lane >> 4, c = lane & 15;
  int n0 = blockIdx.x << 7, m0 = blockIdx.y << 7;
  int wr = w >> 1, wc = w & 1;
  f4v acc[4][4] = {};
  int srow = lane >> 3;
  int sslot = (lane & 7) ^ srow;
  const u16* Abase = A + (m0 + srow) * K + sslot * 8;
  const u16* Bbase = Bt + (n0 + srow) * K + sslot * 8;
  #pragma unroll 1
  for (int kt = 0; kt < K; kt += 64){
    #pragma unroll
    for (int ii = 0; ii < 4; ii++){
      int i = w * 4 + ii;
      gl_lds16(Abase + i * 8 * K + kt, sA + i * 512);
      gl_lds16(Bbase + i * 8 * K + kt, sB + i * 512);
    }
    __syncthreads();
    #pragma unroll
    for (int kk = 0; kk < 2; kk++){
      s8v af[4], bfr[4];
      #pragma unroll
      for (int mi = 0; mi < 4; mi++){
        int r = (wr << 6) + (mi << 4) + c;
        int slot = ((kk << 2) + g) ^ (r & 7);
        af[mi] = *(const s8v*)(sA + r * 64 + slot * 8);
      }
      #pragma unroll
      for (int ni = 0; ni < 4; ni++){
        int r = (wc << 6) + (ni << 4) + c;
        int slot = ((kk << 2) + g) ^ (r & 7);
        bfr[ni] = *(const s8v*)(sB + r * 64 + slot * 8);
      }
      #pragma unroll
      for (int mi = 0; mi < 4; mi++)
        #pragma unroll
        for (int ni = 0; ni < 4; ni++)
          acc[mi][ni] = mfma16(af[mi], bfr[ni], acc[mi][ni]);
    }
    __syncthreads();
  }
  #pragma unroll
  for (int mi = 0; mi < 4; mi++){
    #pragma unroll
    for (int ni = 0; ni < 4; ni++){
      #pragma unroll
      for (int r = 0; r < 4; r++){
        int m = m0 + (wr << 6) + (mi << 4) + (g << 2) + r;
        int n = n0 + (wc << 6) + (ni << 4) + c;
        if (OUTF32) ((float*)Cv)[m * N + n] = acc[mi][ni][r];
        else        ((u16*)Cv)[m * N + n] = f2bf(acc[mi][ni][r]);
      }
    }
  }
}

// ---------------- RMSNorm + RoPE; Q -> stride 96 (zeros 72..95, xlog2e), K -> stride 128 (zeros 72..127) ----------------
__global__ __launch_bounds__(192) void k_normrope(const u16* __restrict__ Y, const float* __restrict__ cosp,
      const float* __restrict__ sinp, const float* __restrict__ qnw, const float* __restrict__ knw,
      u16* __restrict__ Qp, u16* __restrict__ Kp){
  __shared__ float ly[1728];
  int token = blockIdx.x;
  int t = threadIdx.x, head = t >> 3, j = t & 7;
  int base = head * 72 + j * 9;
  const u16* yr = Y + token * 2304;
  float x[9]; float ss = 0.f;
  #pragma unroll
  for (int i = 0; i < 9; i++){ x[i] = bf2f(yr[base + i]); ss += x[i] * x[i]; }
  ss += __shfl_xor(ss, 1); ss += __shfl_xor(ss, 2); ss += __shfl_xor(ss, 4);
  float inv = rsqrtf(ss * (1.f / 72.f) + 1e-6f);
  const float* wn = (head < 16) ? qnw : knw;
  #pragma unroll
  for (int i = 0; i < 9; i++){ int d = j * 9 + i; ly[base + i] = x[i] * inv * (1.f + wn[d]); }
  __syncthreads();
  const float* cs = cosp + token * 72;
  const float* sn = sinp + token * 72;
  float scale = (head < 16) ? 1.4426950408889634f : 1.0f;
  float o[9];
  #pragma unroll
  for (int i = 0; i < 9; i++){
    int d = j * 9 + i;
    int dm = (d >= 36) ? d - 36 : d;
    float rot = (dm < 18) ? -ly[head * 72 + d + 18] : ly[head * 72 + d - 18];
    o[i] = (ly[base + i] * cs[d] + rot * sn[d]) * scale;
  }
  int b = token >> 11, s = token & 2047;
  if (head < 16){
    u16* dst = Qp + (size_t)(((b << 4) + head) * 2048 + s) * 96;
    #pragma unroll
    for (int i = 0; i < 9; i++) dst[j * 9 + i] = f2bf(o[i]);
    #pragma unroll
    for (int p2 = 0; p2 < 3; p2++) dst[72 + j * 3 + p2] = 0;
  } else {
    u16* dst = Kp + (size_t)(((b << 3) + (head - 16)) * 2048 + s) * 128;
    #pragma unroll
    for (int i = 0; i < 9; i++) dst[j * 9 + i] = f2bf(o[i]);
    #pragma unroll
    for (int p2 = 0; p2 < 7; p2++) dst[72 + j * 7 + p2] = 0;
  }
}

// ---------------- V: RMSNorm (no scale) + transpose -> Vt [4][8][72][2048] ----------------
__global__ __launch_bounds__(256) void k_vtrans(const u16* __restrict__ Y, u16* __restrict__ Vt){
  __shared__ float lv[72][33];
  int st = blockIdx.x, bk = blockIdx.y;
  int b = bk >> 3, kvh = bk & 7;
  int t = threadIdx.x, tl = t >> 3, j = t & 7;
  int token = (b << 11) + (st << 5) + tl;
  const u16* yr = Y + token * 2304 + 1728 + kvh * 72 + j * 9;
  float x[9]; float ss = 0.f;
  #pragma unroll
  for (int i = 0; i < 9; i++){ x[i] = bf2f(yr[i]); ss += x[i] * x[i]; }
  ss += __shfl_xor(ss, 1); ss += __shfl_xor(ss, 2); ss += __shfl_xor(ss, 4);
  float inv = rsqrtf(ss * (1.f / 72.f) + 1e-6f);
  #pragma unroll
  for (int i = 0; i < 9; i++) lv[j * 9 + i][tl] = x[i] * inv;
  __syncthreads();
  u16* vb = Vt + bk * 72 * 2048 + (st << 5);
  for (int e = t; e < 72 * 32; e += 256){
    int r = e >> 5, cl = e & 31;
    vb[r * 2048 + cl] = f2bf(lv[r][cl]);
  }
}

// ---------------- Flash attention: double-buffered K/V, XOR-swizzled LDS ----------------
#define SPS 88
__global__ __launch_bounds__(512) void k_attn(const u16* __restrict__ Qp, const u16* __restrict__ Kp,
                                              const u16* __restrict__ Vt, u16* __restrict__ O){
  __shared__ u16 sK[2][2][64 * 64];   // [dbuf][d-half][row*64], XOR-swizzled slots
  __shared__ u16 sV[2][80 * 64];      // [dbuf][d-row*64], rows 72..79 garbage (row-isolated)
  __shared__ u16 sP[8][16 * SPS];
  int tid = threadIdx.x, w = tid >> 6, lane = tid & 63, g = lane >> 4, c = lane & 15, x = c & 7;
  int qt = blockIdx.x, bh = blockIdx.y, b = bh >> 4, h = bh & 15, kv = h >> 1;
  int qrow = (qt << 7) + (w << 4) + c;
  const u16* qb = Qp + (size_t)((((b << 4) + h) << 11) + qrow) * 96 + g * 8;
  s8v qf[3];
  #pragma unroll
  for (int kk = 0; kk < 3; kk++) qf[kk] = *(const s8v*)(qb + kk * 32);
  f4v ao[5] = {};
  float mv = -3.0e38f, lsp = 0.f;
  const char* kbase = (const char*)(Kp + ((size_t)((b << 3) + kv) << 11) * 128);
  const u16* vbase = Vt + (size_t)((b << 3) + kv) * 72 * 2048;
  u16* myP = &sP[w][0];
  u16* pw = myP + c * SPS + g * 4;
  const u16* prd = myP + c * SPS + g * 8;
  // staging lane geometry
  int sr = lane >> 3, ss = lane & 7, sx = (ss ^ (sr & 7));          // K: 8 rows x 8 slots
  int vr0 = tid >> 3, vs0 = tid & 7, vsw = (vs0 ^ (vr0 & 7));      // V: row, slot, swizzled slot
  bool has1 = (tid < 64);                                           // second V element (rows 64..71)
  const u16* vsrc0 = vbase + vr0 * 2048 + vs0 * 8;
  const u16* vsrc1 = vbase + (vr0 + 64) * 2048 + vs0 * 8;
  u16* vdst0o = &sV[0][0] + vr0 * 64 + vsw * 8;                     // offset within a buffer
  u16* vdst1o = &sV[0][0] + (vr0 + 64) * 64 + vsw * 8;
  size_t vbufstep = (size_t)(&sV[1][0] - &sV[0][0]);

  // ---- prologue: stage tile 0 ----
  #pragma unroll
  for (int i = w; i < 16; i += 8){
    int hf = i >> 3, i8 = i & 7;
    gl_lds16(kbase + (i8 * 8 + sr) * 256 + hf * 128 + sx * 16,
             (char*)&sK[0][hf][0] + i8 * 1024 + (size_t)lane * 16);
  }
  {
    u32x4 v0 = *(const u32x4*)(vsrc0);
    u32x4 v1{};
    if (has1) v1 = *(const u32x4*)(vsrc1);
    *(u32x4*)(vdst0o) = v0;
    if (has1) *(u32x4*)(vdst1o) = v1;
  }
  __syncthreads();

  #pragma unroll 1
  for (int t = 0; t < 32; t++){
    int cur = t & 1, nxt = cur ^ 1;
    bool hasn = (t < 31);
    u32x4 v0{}, v1{};
    if (hasn){
      const char* kn = kbase + (size_t)(t + 1) * 64 * 256;
      #pragma unroll
      for (int i = w; i < 16; i += 8){
        int hf = i >> 3, i8 = i & 7;
        gl_lds16(kn + (i8 * 8 + sr) * 256 + hf * 128 + sx * 16,
                 (char*)&sK[nxt][hf][0] + i8 * 1024 + (size_t)lane * 16);
      }
      int ktn = (t + 1) << 6;
      v0 = *(const u32x4*)(vsrc0 + ktn);
      if (has1) v1 = *(const u32x4*)(vsrc1 + ktn);
    }
    // ---- QK^T from sK[cur] ----
    const u16* sKa = &sK[cur][0][0];
    const u16* sKb = &sK[cur][1][0];
    f4v sc[4] = {};
    __builtin_amdgcn_s_setprio(1);
    #pragma unroll
    for (int mt = 0; mt < 4; mt++){
      int r = mt * 16 + c;
      s8v k0 = *(const s8v*)(sKa + r * 64 + ((g ^ x) << 3));
      s8v k1 = *(const s8v*)(sKa + r * 64 + (((4 + g) ^ x) << 3));
      s8v k2 = *(const s8v*)(sKb + r * 64 + ((g ^ x) << 3));
      sc[mt] = mfma16(k0, qf[0], sc[mt]);
      sc[mt] = mfma16(k1, qf[1], sc[mt]);
      sc[mt] = mfma16(k2, qf[2], sc[mt]);
    }
    __builtin_amdgcn_s_setprio(0);
    // ---- online softmax (exp2 domain) ----
    float tm = -3.0e38f;
    #pragma unroll
    for (int mt = 0; mt < 4; mt++){
      float a0 = fmaxf(sc[mt][0], sc[mt][1]), a1 = fmaxf(sc[mt][2], sc[mt][3]);
      tm = fmaxf(tm, fmaxf(a0, a1));
    }
    tm = fmaxf(tm, __shfl_xor(tm, 16));
    tm = fmaxf(tm, __shfl_xor(tm, 32));
    if (!__all(tm <= mv + 8.f)){
      float mn = fmaxf(mv, tm);
      float scl = exp2f(mv - mn);
      lsp *= scl;
      #pragma unroll
      for (int db = 0; db < 5; db++)
        #pragma unroll
        for (int r = 0; r < 4; r++) ao[db][r] *= scl;
      mv = mn;
    }
    float ts = 0.f;
    #pragma unroll
    for (int mt = 0; mt < 4; mt++){
      float p0 = exp2f(sc[mt][0] - mv), p1 = exp2f(sc[mt][1] - mv);
      float p2 = exp2f(sc[mt][2] - mv), p3 = exp2f(sc[mt][3] - mv);
      ts += (p0 + p1) + (p2 + p3);
      u32x2 pk; pk.x = cvtpk(p0, p1); pk.y = cvtpk(p2, p3);
      *(u32x2*)(pw + mt * 16) = pk;
    }
    lsp += ts;
    // ---- PV from sV[cur] ----
    const u16* sVc = &sV[cur][0];
    __builtin_amdgcn_s_setprio(1);
    #pragma unroll
    for (int k2 = 0; k2 < 2; k2++){
      s8v pf = *(const s8v*)(prd + k2 * 32);
      #pragma unroll
      for (int db = 0; db < 5; db++){
        s8v vf = *(const s8v*)(sVc + (db * 16 + c) * 64 + ((((k2 << 2) + g) ^ x) << 3));
        ao[db] = mfma16(vf, pf, ao[db]);
      }
    }
    __builtin_amdgcn_s_setprio(0);
    // ---- land V prefetch into sV[nxt] ----
    if (hasn){
      *(u32x4*)(vdst0o + (size_t)nxt * vbufstep) = v0;
      if (has1) *(u32x4*)(vdst1o + (size_t)nxt * vbufstep) = v1;
    }
    __syncthreads();
  }
  float ls = lsp;
  ls += __shfl_xor(ls, 16);
  ls += __shfl_xor(ls, 32);
  float inv = 1.f / ls;
  u16* ob = O + (size_t)((((b << 11) + qrow) << 4) + h) * 72;
  #pragma unroll
  for (int db = 0; db < 5; db++){
    #pragma unroll
    for (int pr2 = 0; pr2 < 2; pr2++){
      int dd = db * 16 + g * 4 + pr2 * 2;
      if (dd < 72)
        *(u32*)(ob + dd) = cvtpk(ao[db][pr2 * 2] * inv, ao[db][pr2 * 2 + 1] * inv);
    }
  }
}

// ---------------- launch ----------------
extern "C" void kernel_launch(void* const* d_in, const int* in_sizes, int n_in,
                              void* d_out, int out_size, void* d_ws, size_t ws_size,
                              hipStream_t stream){
  (void)in_sizes; (void)n_in; (void)out_size; (void)ws_size;
  const float* hs   = (const float*)d_in[0];
  const float* cosp = (const float*)d_in[1];
  const float* sinp = (const float*)d_in[2];
  const float* Wq   = (const float*)d_in[5];
  const float* Wk   = (const float*)d_in[6];
  const float* Wv   = (const float*)d_in[7];
  const float* Wo   = (const float*)d_in[8];
  const float* qnw  = (const float*)d_in[9];
  const float* knw  = (const float*)d_in[10];
  char* ws = (char*)d_ws;
  u16* Xb    = (u16*)(ws);                    // 18,874,368 B (reused as O after gemm1)
  u16* WtQKV = (u16*)(ws + 18874368);         //  5,308,416 B
  u16* Wot   = (u16*)(ws + 24182784);         //  2,654,208 B
  u16* Y     = (u16*)(ws + 26836992);         // 37,748,736 B
  u16* Qp    = (u16*)(ws + 64585728);         // 25,165,824 B (stride 96)
  u16* Kp    = (u16*)(ws + 89751552);         // 16,777,216 B (stride 128)
  u16* Vt    = (u16*)(ws + 106528768);        //  9,437,184 B  (total 115,965,952)
  u16* O     = Xb;

  k_prepx<<<4608, 256, 0, stream>>>(hs, Xb, 8192 * 1152);
  k_transpose<<<36 * 36, 256, 0, stream>>>(Wq, WtQKV, 1152, 1152, 1152);
  k_transpose<<<36 * 18, 256, 0, stream>>>(Wk, WtQKV + 1152 * 1152, 1152, 576, 1152);
  k_transpose<<<36 * 18, 256, 0, stream>>>(Wv, WtQKV + 1728 * 1152, 1152, 576, 1152);
  k_transpose<<<36 * 36, 256, 0, stream>>>(Wo, Wot, 1152, 1152, 1152);
  k_gemm<0><<<dim3(18, 64), 256, 0, stream>>>(Xb, WtQKV, Y, 8192, 2304, 1152);
  k_normrope<<<8192, 192, 0, stream>>>(Y, cosp, sinp, qnw, knw, Qp, Kp);
  k_vtrans<<<dim3(64, 32), 256, 0, stream>>>(Y, Vt);
  k_attn<<<dim3(16, 64), 512, 0, stream>>>(Qp, Kp, Vt, O);
  k_gemm<1><<<dim3(9, 64), 256, 0, stream>>>(O, Wot, (float*)d_out, 8192, 1152, 1152);
}

// Round 4
// 324.892 us; speedup vs baseline: 1.0799x; 1.0098x over previous
//
#include <hip/hip_runtime.h>

typedef unsigned int u32;
typedef unsigned short u16;
typedef __attribute__((ext_vector_type(8))) short s8v;
typedef __attribute__((ext_vector_type(8))) __bf16 b8v;
typedef __attribute__((ext_vector_type(4))) float f4v;
typedef __attribute__((ext_vector_type(16))) float f32x16;
typedef __attribute__((ext_vector_type(4))) u32 u32x4;
typedef __attribute__((ext_vector_type(2))) u32 u32x2;

#define DEV static __device__ __forceinline__

DEV u32 cvtpk(float a, float b){ u32 r; asm("v_cvt_pk_bf16_f32 %0, %1, %2" : "=v"(r) : "v"(a), "v"(b)); return r; }
DEV u16 f2bf(float x){ return (u16)(cvtpk(x, x) & 0xffffu); }
DEV float bf2f(u16 u){ return __builtin_bit_cast(float, ((u32)u) << 16); }

DEV f4v mfma16(s8v a, s8v b, f4v c){
  return __builtin_amdgcn_mfma_f32_16x16x32_bf16(__builtin_bit_cast(b8v, a), __builtin_bit_cast(b8v, b), c, 0, 0, 0);
}
DEV f32x16 mfma32(s8v a, s8v b, f32x16 c){
  return __builtin_amdgcn_mfma_f32_32x32x16_bf16(__builtin_bit_cast(b8v, a), __builtin_bit_cast(b8v, b), c, 0, 0, 0);
}

DEV void gl_lds16(const void* g, void* l){
  __builtin_amdgcn_global_load_lds((const __attribute__((address_space(1))) u32*)g,
                                   (__attribute__((address_space(3))) u32*)l, 16, 0, 0);
}

// ---------------- prep: X fp32 -> bf16 ----------------
__global__ __launch_bounds__(256) void k_prepx(const float* __restrict__ x, u16* __restrict__ xb, int n){
  int i = (blockIdx.x * 256 + threadIdx.x) * 8;
  if (i >= n) return;
  float4 a = *(const float4*)(x + i);
  float4 b = *(const float4*)(x + i + 4);
  u32x4 o;
  o.x = cvtpk(a.x, a.y); o.y = cvtpk(a.z, a.w);
  o.z = cvtpk(b.x, b.y); o.w = cvtpk(b.z, b.w);
  *(u32x4*)(xb + i) = o;
}

// ---------------- prep: transpose fp32 [K][N] -> bf16 [N][K] (ldd) ----------------
__global__ __launch_bounds__(256) void k_transpose(const float* __restrict__ src, u16* __restrict__ dst,
                                                   int K, int N, int ldd){
  __shared__ float t[32][33];
  int nt = N >> 5;
  int k0 = (blockIdx.x / nt) << 5, n0 = (blockIdx.x % nt) << 5;
  int col = threadIdx.x & 31, rw = threadIdx.x >> 5;
  #pragma unroll
  for (int i = 0; i < 4; i++){ int r = rw + i * 8; t[r][col] = src[(k0 + r) * N + n0 + col]; }
  __syncthreads();
  #pragma unroll
  for (int i = 0; i < 4; i++){ int r = rw + i * 8; dst[(n0 + r) * ldd + k0 + col] = f2bf(t[col][r]); }
}

// ---------------- GEMM: C[M,N] = A[M,K] * Bt[N,K]^T, bf16 in, bf16 or f32 out ----------------
template<int OUTF32>
__global__ __launch_bounds__(256) void k_gemm(const u16* __restrict__ A, const u16* __restrict__ Bt,
                                              void* __restrict__ Cv, int M, int N, int K){
  __shared__ u16 sA[128 * 64];
  __shared__ u16 sB[128 * 64];
  int tid = threadIdx.x, w = tid >> 6, lane = tid & 63, g = lane >> 4, c = lane & 15;
  int n0 = blockIdx.x << 7, m0 = blockIdx.y << 7;
  int wr = w >> 1, wc = w & 1;
  f4v acc[4][4] = {};
  int srow = lane >> 3;
  int sslot = (lane & 7) ^ srow;
  const u16* Abase = A + (m0 + srow) * K + sslot * 8;
  const u16* Bbase = Bt + (n0 + srow) * K + sslot * 8;
  #pragma unroll 1
  for (int kt = 0; kt < K; kt += 64){
    #pragma unroll
    for (int ii = 0; ii < 4; ii++){
      int i = w * 4 + ii;
      gl_lds16(Abase + i * 8 * K + kt, sA + i * 512);
      gl_lds16(Bbase + i * 8 * K + kt, sB + i * 512);
    }
    __syncthreads();
    #pragma unroll
    for (int kk = 0; kk < 2; kk++){
      s8v af[4], bfr[4];
      #pragma unroll
      for (int mi = 0; mi < 4; mi++){
        int r = (wr << 6) + (mi << 4) + c;
        int slot = ((kk << 2) + g) ^ (r & 7);
        af[mi] = *(const s8v*)(sA + r * 64 + slot * 8);
      }
      #pragma unroll
      for (int ni = 0; ni < 4; ni++){
        int r = (wc << 6) + (ni << 4) + c;
        int slot = ((kk << 2) + g) ^ (r & 7);
        bfr[ni] = *(const s8v*)(sB + r * 64 + slot * 8);
      }
      #pragma unroll
      for (int mi = 0; mi < 4; mi++)
        #pragma unroll
        for (int ni = 0; ni < 4; ni++)
          acc[mi][ni] = mfma16(af[mi], bfr[ni], acc[mi][ni]);
    }
    __syncthreads();
  }
  #pragma unroll
  for (int mi = 0; mi < 4; mi++){
    #pragma unroll
    for (int ni = 0; ni < 4; ni++){
      #pragma unroll
      for (int r = 0; r < 4; r++){
        int m = m0 + (wr << 6) + (mi << 4) + (g << 2) + r;
        int n = n0 + (wc << 6) + (ni << 4) + c;
        if (OUTF32) ((float*)Cv)[m * N + n] = acc[mi][ni][r];
        else        ((u16*)Cv)[m * N + n] = f2bf(acc[mi][ni][r]);
      }
    }
  }
}

// ---------------- RMSNorm + RoPE; Q -> stride 96 (zeros 72..95, xlog2e), K -> stride 128 (zeros 72..127) ----------------
__global__ __launch_bounds__(192) void k_normrope(const u16* __restrict__ Y, const float* __restrict__ cosp,
      const float* __restrict__ sinp, const float* __restrict__ qnw, const float* __restrict__ knw,
      u16* __restrict__ Qp, u16* __restrict__ Kp){
  __shared__ float ly[1728];
  int token = blockIdx.x;
  int t = threadIdx.x, head = t >> 3, j = t & 7;
  int base = head * 72 + j * 9;
  const u16* yr = Y + token * 2304;
  float x[9]; float ss = 0.f;
  #pragma unroll
  for (int i = 0; i < 9; i++){ x[i] = bf2f(yr[base + i]); ss += x[i] * x[i]; }
  ss += __shfl_xor(ss, 1); ss += __shfl_xor(ss, 2); ss += __shfl_xor(ss, 4);
  float inv = rsqrtf(ss * (1.f / 72.f) + 1e-6f);
  const float* wn = (head < 16) ? qnw : knw;
  #pragma unroll
  for (int i = 0; i < 9; i++){ int d = j * 9 + i; ly[base + i] = x[i] * inv * (1.f + wn[d]); }
  __syncthreads();
  const float* cs = cosp + token * 72;
  const float* sn = sinp + token * 72;
  float scale = (head < 16) ? 1.4426950408889634f : 1.0f;
  float o[9];
  #pragma unroll
  for (int i = 0; i < 9; i++){
    int d = j * 9 + i;
    int dm = (d >= 36) ? d - 36 : d;
    float rot = (dm < 18) ? -ly[head * 72 + d + 18] : ly[head * 72 + d - 18];
    o[i] = (ly[base + i] * cs[d] + rot * sn[d]) * scale;
  }
  int b = token >> 11, s = token & 2047;
  if (head < 16){
    u16* dst = Qp + (size_t)(((b << 4) + head) * 2048 + s) * 96;
    #pragma unroll
    for (int i = 0; i < 9; i++) dst[j * 9 + i] = f2bf(o[i]);
    #pragma unroll
    for (int p2 = 0; p2 < 3; p2++) dst[72 + j * 3 + p2] = 0;
  } else {
    u16* dst = Kp + (size_t)(((b << 3) + (head - 16)) * 2048 + s) * 128;
    #pragma unroll
    for (int i = 0; i < 9; i++) dst[j * 9 + i] = f2bf(o[i]);
    #pragma unroll
    for (int p2 = 0; p2 < 7; p2++) dst[72 + j * 7 + p2] = 0;
  }
}

// ---------------- V: RMSNorm (no scale) + transpose -> Vt [4][8][72][2048] ----------------
__global__ __launch_bounds__(256) void k_vtrans(const u16* __restrict__ Y, u16* __restrict__ Vt){
  __shared__ float lv[72][33];
  int st = blockIdx.x, bk = blockIdx.y;
  int b = bk >> 3, kvh = bk & 7;
  int t = threadIdx.x, tl = t >> 3, j = t & 7;
  int token = (b << 11) + (st << 5) + tl;
  const u16* yr = Y + token * 2304 + 1728 + kvh * 72 + j * 9;
  float x[9]; float ss = 0.f;
  #pragma unroll
  for (int i = 0; i < 9; i++){ x[i] = bf2f(yr[i]); ss += x[i] * x[i]; }
  ss += __shfl_xor(ss, 1); ss += __shfl_xor(ss, 2); ss += __shfl_xor(ss, 4);
  float inv = rsqrtf(ss * (1.f / 72.f) + 1e-6f);
  #pragma unroll
  for (int i = 0; i < 9; i++) lv[j * 9 + i][tl] = x[i] * inv;
  __syncthreads();
  u16* vb = Vt + bk * 72 * 2048 + (st << 5);
  for (int e = t; e < 72 * 32; e += 256){
    int r = e >> 5, cl = e & 31;
    vb[r * 2048 + cl] = f2bf(lv[r][cl]);
  }
}

// ---------------- Flash attention, 32x32x16 MFMA, P in-register via permlane32_swap ----------------
// grid (8 qtiles of 256, 64 b*h). 8 waves x 32 q-rows. KT=64 keys/iter.
__global__ __launch_bounds__(512, 4) void k_attn(const u16* __restrict__ Qp, const u16* __restrict__ Kp,
                                                 const u16* __restrict__ Vt, u16* __restrict__ O){
  __shared__ u16 sK[2][64 * 128];   // [buf][key][16 slots of 8 u16]; phys slot = s ^ (key&15)
  __shared__ u16 sV[2][96 * 64];    // [buf][d][8 slots of 8 u16]; phys = s ^ (d&7); rows 72..95 garbage
  int tid = threadIdx.x, w = tid >> 6, lane = tid & 63, hi = lane >> 5, l31 = lane & 31;
  int qt = blockIdx.x, bh = blockIdx.y, b = bh >> 4, h = bh & 15, kv = h >> 1;
  int q = (qt << 8) + (w << 5) + l31;
  const u16* qb = Qp + (size_t)((((b << 4) + h) << 11) + q) * 96;
  s8v qf[5];
  #pragma unroll
  for (int ds = 0; ds < 5; ds++) qf[ds] = *(const s8v*)(qb + ds * 16 + hi * 8);
  f32x16 ao[3] = {};
  float mv = -3.0e38f, lsp = 0.f;
  const char* kb = (const char*)Kp + (((size_t)((b << 3) + kv)) << 11) * 256;
  const char* vb = (const char*)Vt + (size_t)((b << 3) + kv) * 72 * 4096;
  // K staging geometry: 1024 chunks of 16B; wave w does i=0,1 -> chunks (i*8+w)*64+lane
  int kn0 = (0 * 8 + w) * 64 + lane, kn1 = (1 * 8 + w) * 64 + lane;
  int kr0 = kn0 >> 4, kr1 = kn1 >> 4;
  int ksrc0 = kr0 * 256 + (((lane & 15) ^ (kr0 & 15)) << 4);
  int ksrc1 = kr1 * 256 + (((lane & 15) ^ (kr1 & 15)) << 4);
  int kdst0 = kn0 << 4, kdst1 = kn1 << 4;
  // V staging: 576 chunks; wave w does i=w (and i=8 for w==0)
  int vn0 = w * 64 + lane, vn1 = 512 + lane;
  int vr0 = vn0 >> 3, vr1 = vn1 >> 3;
  int vsrc0 = vr0 * 4096 + (((lane & 7) ^ (vr0 & 7)) << 4);
  int vsrc1 = vr1 * 4096 + (((lane & 7) ^ (vr1 & 7)) << 4);
  int vdst0 = vn0 << 4, vdst1 = vn1 << 4;

#define STAGE_KV(buf, t1) { \
    const char* kt_ = kb + (size_t)(t1) * 16384; \
    gl_lds16(kt_ + ksrc0, (char*)sK[buf] + kdst0); \
    gl_lds16(kt_ + ksrc1, (char*)sK[buf] + kdst1); \
    const char* vt_ = vb + (size_t)(t1) * 128; \
    gl_lds16(vt_ + vsrc0, (char*)sV[buf] + vdst0); \
    if (w == 0) gl_lds16(vt_ + vsrc1, (char*)sV[buf] + vdst1); }

  STAGE_KV(0, 0)
  __syncthreads();

  #pragma unroll 1
  for (int t = 0; t < 32; t++){
    int cur = t & 1, nxt = cur ^ 1;
    if (t < 31){ STAGE_KV(nxt, t + 1) }
    // ---- QK^T: C[key][q], 2 key-tiles ----
    const u16* sKc = sK[cur];
    f32x16 s0 = {}, s1 = {};
    __builtin_amdgcn_s_setprio(1);
    #pragma unroll
    for (int ds = 0; ds < 5; ds++){
      int s = ds * 2 + hi;
      int r0 = l31, r1 = 32 + l31;
      s8v k0 = *(const s8v*)(sKc + r0 * 128 + ((s ^ (r0 & 15)) << 3));
      s8v k1 = *(const s8v*)(sKc + r1 * 128 + ((s ^ (r1 & 15)) << 3));
      s0 = mfma32(k0, qf[ds], s0);
      s1 = mfma32(k1, qf[ds], s1);
    }
    __builtin_amdgcn_s_setprio(0);
    // ---- online softmax (exp2 domain), per-lane 32 scores of column q ----
    float tm = s0[0];
    #pragma unroll
    for (int i = 1; i < 16; i++) tm = fmaxf(tm, s0[i]);
    #pragma unroll
    for (int i = 0; i < 16; i++) tm = fmaxf(tm, s1[i]);
    tm = fmaxf(tm, __shfl_xor(tm, 32));
    if (!__all(tm <= mv + 8.f)){
      float mn = fmaxf(mv, tm);
      float scl = exp2f(mv - mn);
      lsp *= scl;
      ao[0] *= scl; ao[1] *= scl; ao[2] *= scl;
      mv = mn;
    }
    float ts = 0.f;
    #pragma unroll
    for (int i = 0; i < 16; i++){ float e = exp2f(s0[i] - mv); s0[i] = e; ts += e; }
    #pragma unroll
    for (int i = 0; i < 16; i++){ float e = exp2f(s1[i] - mv); s1[i] = e; ts += e; }
    lsp += ts;
    // ---- P -> PV B-frags in-register (cvt_pk + permlane32_swap) ----
    s8v pf[4];
#define MK_PF(S, ks) { \
      const int blo = ((ks) & 1) * 8; \
      u32 a0 = cvtpk(S[blo + 0], S[blo + 1]); \
      u32 a1 = cvtpk(S[blo + 2], S[blo + 3]); \
      u32 b0 = cvtpk(S[blo + 4], S[blo + 5]); \
      u32 b1 = cvtpk(S[blo + 6], S[blo + 7]); \
      asm("v_permlane32_swap_b32 %0, %1" : "+v"(a0), "+v"(b0)); \
      asm("v_permlane32_swap_b32 %0, %1" : "+v"(a1), "+v"(b1)); \
      u32x4 w4 = {a0, a1, b0, b1}; \
      pf[ks] = __builtin_bit_cast(s8v, w4); }
    MK_PF(s0, 0) MK_PF(s0, 1) MK_PF(s1, 2) MK_PF(s1, 3)
#undef MK_PF
    // ---- PV: C[d][q] += Vt[d][k] * P[k][q] ----
    const u16* sVc = sV[cur];
    __builtin_amdgcn_s_setprio(1);
    #pragma unroll
    for (int ks = 0; ks < 4; ks++){
      int s = ks * 2 + hi;
      #pragma unroll
      for (int dt = 0; dt < 3; dt++){
        int r = dt * 32 + l31;
        s8v vf = *(const s8v*)(sVc + r * 64 + ((s ^ (r & 7)) << 3));
        ao[dt] = mfma32(vf, pf[ks], ao[dt]);
      }
    }
    __builtin_amdgcn_s_setprio(0);
    __syncthreads();
  }
  float ls = lsp + __shfl_xor(lsp, 32);
  float inv = 1.f / ls;
  u16* ob = O + (size_t)((((b << 11) + q) << 4) + h) * 72;
  #pragma unroll
  for (int dt = 0; dt < 3; dt++){
    #pragma unroll
    for (int gp = 0; gp < 4; gp++){
      int d = dt * 32 + gp * 8 + hi * 4;
      if (d < 72){
        u32x2 o2;
        o2.x = cvtpk(ao[dt][gp * 4 + 0] * inv, ao[dt][gp * 4 + 1] * inv);
        o2.y = cvtpk(ao[dt][gp * 4 + 2] * inv, ao[dt][gp * 4 + 3] * inv);
        *(u32x2*)(ob + d) = o2;
      }
    }
  }
#undef STAGE_KV
}

// ---------------- launch ----------------
extern "C" void kernel_launch(void* const* d_in, const int* in_sizes, int n_in,
                              void* d_out, int out_size, void* d_ws, size_t ws_size,
                              hipStream_t stream){
  (void)in_sizes; (void)n_in; (void)out_size; (void)ws_size;
  const float* hs   = (const float*)d_in[0];
  const float* cosp = (const float*)d_in[1];
  const float* sinp = (const float*)d_in[2];
  const float* Wq   = (const float*)d_in[5];
  const float* Wk   = (const float*)d_in[6];
  const float* Wv   = (const float*)d_in[7];
  const float* Wo   = (const float*)d_in[8];
  const float* qnw  = (const float*)d_in[9];
  const float* knw  = (const float*)d_in[10];
  char* ws = (char*)d_ws;
  u16* Xb    = (u16*)(ws);                    // 18,874,368 B (reused as O after gemm1)
  u16* WtQKV = (u16*)(ws + 18874368);         //  5,308,416 B
  u16* Wot   = (u16*)(ws + 24182784);         //  2,654,208 B
  u16* Y     = (u16*)(ws + 26836992);         // 37,748,736 B
  u16* Qp    = (u16*)(ws + 64585728);         // 25,165,824 B (stride 96)
  u16* Kp    = (u16*)(ws + 89751552);         // 16,777,216 B (stride 128)
  u16* Vt    = (u16*)(ws + 106528768);        //  9,437,184 B  (total 115,965,952)
  u16* O     = Xb;

  k_prepx<<<4608, 256, 0, stream>>>(hs, Xb, 8192 * 1152);
  k_transpose<<<36 * 36, 256, 0, stream>>>(Wq, WtQKV, 1152, 1152, 1152);
  k_transpose<<<36 * 18, 256, 0, stream>>>(Wk, WtQKV + 1152 * 1152, 1152, 576, 1152);
  k_transpose<<<36 * 18, 256, 0, stream>>>(Wv, WtQKV + 1728 * 1152, 1152, 576, 1152);
  k_transpose<<<36 * 36, 256, 0, stream>>>(Wo, Wot, 1152, 1152, 1152);
  k_gemm<0><<<dim3(18, 64), 256, 0, stream>>>(Xb, WtQKV, Y, 8192, 2304, 1152);
  k_normrope<<<8192, 192, 0, stream>>>(Y, cosp, sinp, qnw, knw, Qp, Kp);
  k_vtrans<<<dim3(64, 32), 256, 0, stream>>>(Y, Vt);
  k_attn<<<dim3(8, 64), 512, 0, stream>>>(Qp, Kp, Vt, O);
  k_gemm<1><<<dim3(9, 64), 256, 0, stream>>>(O, Wot, (float*)d_out, 8192, 1152, 1152);
}

// Round 5
// 316.538 us; speedup vs baseline: 1.1084x; 1.0264x over previous
//
#include <hip/hip_runtime.h>

typedef unsigned int u32;
typedef unsigned short u16;
typedef __attribute__((ext_vector_type(8))) short s8v;
typedef __attribute__((ext_vector_type(8))) __bf16 b8v;
typedef __attribute__((ext_vector_type(4))) float f4v;
typedef __attribute__((ext_vector_type(16))) float f32x16;
typedef __attribute__((ext_vector_type(4))) u32 u32x4;
typedef __attribute__((ext_vector_type(2))) u32 u32x2;

#define DEV static __device__ __forceinline__

DEV u32 cvtpk(float a, float b){ u32 r; asm("v_cvt_pk_bf16_f32 %0, %1, %2" : "=v"(r) : "v"(a), "v"(b)); return r; }
DEV u16 f2bf(float x){ return (u16)(cvtpk(x, x) & 0xffffu); }
DEV float bf2f(u16 u){ return __builtin_bit_cast(float, ((u32)u) << 16); }

DEV f4v mfma16(s8v a, s8v b, f4v c){
  return __builtin_amdgcn_mfma_f32_16x16x32_bf16(__builtin_bit_cast(b8v, a), __builtin_bit_cast(b8v, b), c, 0, 0, 0);
}
DEV f32x16 mfma32(s8v a, s8v b, f32x16 c){
  return __builtin_amdgcn_mfma_f32_32x32x16_bf16(__builtin_bit_cast(b8v, a), __builtin_bit_cast(b8v, b), c, 0, 0, 0);
}

DEV void gl_lds16(const void* g, void* l){
  __builtin_amdgcn_global_load_lds((const __attribute__((address_space(1))) u32*)g,
                                   (__attribute__((address_space(3))) u32*)l, 16, 0, 0);
}

// ---------------- prep: X fp32 -> bf16 ----------------
__global__ __launch_bounds__(256) void k_prepx(const float* __restrict__ x, u16* __restrict__ xb, int n){
  int i = (blockIdx.x * 256 + threadIdx.x) * 8;
  if (i >= n) return;
  float4 a = *(const float4*)(x + i);
  float4 b = *(const float4*)(x + i + 4);
  u32x4 o;
  o.x = cvtpk(a.x, a.y); o.y = cvtpk(a.z, a.w);
  o.z = cvtpk(b.x, b.y); o.w = cvtpk(b.z, b.w);
  *(u32x4*)(xb + i) = o;
}

// ---------------- prep: transpose fp32 [K][N] -> bf16 [N][K] (ldd) ----------------
__global__ __launch_bounds__(256) void k_transpose(const float* __restrict__ src, u16* __restrict__ dst,
                                                   int K, int N, int ldd){
  __shared__ float t[32][33];
  int nt = N >> 5;
  int k0 = (blockIdx.x / nt) << 5, n0 = (blockIdx.x % nt) << 5;
  int col = threadIdx.x & 31, rw = threadIdx.x >> 5;
  #pragma unroll
  for (int i = 0; i < 4; i++){ int r = rw + i * 8; t[r][col] = src[(k0 + r) * N + n0 + col]; }
  __syncthreads();
  #pragma unroll
  for (int i = 0; i < 4; i++){ int r = rw + i * 8; dst[(n0 + r) * ldd + k0 + col] = f2bf(t[col][r]); }
}

// ---------------- GEMM: C[M,N] = A[M,K] * Bt[N,K]^T, bf16 in, bf16 or f32 out ----------------
template<int OUTF32>
__global__ __launch_bounds__(256) void k_gemm(const u16* __restrict__ A, const u16* __restrict__ Bt,
                                              void* __restrict__ Cv, int M, int N, int K){
  __shared__ u16 sA[128 * 64];
  __shared__ u16 sB[128 * 64];
  int tid = threadIdx.x, w = tid >> 6, lane = tid & 63, g = lane >> 4, c = lane & 15;
  int n0 = blockIdx.x << 7, m0 = blockIdx.y << 7;
  int wr = w >> 1, wc = w & 1;
  f4v acc[4][4] = {};
  int srow = lane >> 3;
  int sslot = (lane & 7) ^ srow;
  const u16* Abase = A + (m0 + srow) * K + sslot * 8;
  const u16* Bbase = Bt + (n0 + srow) * K + sslot * 8;
  #pragma unroll 1
  for (int kt = 0; kt < K; kt += 64){
    #pragma unroll
    for (int ii = 0; ii < 4; ii++){
      int i = w * 4 + ii;
      gl_lds16(Abase + i * 8 * K + kt, sA + i * 512);
      gl_lds16(Bbase + i * 8 * K + kt, sB + i * 512);
    }
    __syncthreads();
    #pragma unroll
    for (int kk = 0; kk < 2; kk++){
      s8v af[4], bfr[4];
      #pragma unroll
      for (int mi = 0; mi < 4; mi++){
        int r = (wr << 6) + (mi << 4) + c;
        int slot = ((kk << 2) + g) ^ (r & 7);
        af[mi] = *(const s8v*)(sA + r * 64 + slot * 8);
      }
      #pragma unroll
      for (int ni = 0; ni < 4; ni++){
        int r = (wc << 6) + (ni << 4) + c;
        int slot = ((kk << 2) + g) ^ (r & 7);
        bfr[ni] = *(const s8v*)(sB + r * 64 + slot * 8);
      }
      #pragma unroll
      for (int mi = 0; mi < 4; mi++)
        #pragma unroll
        for (int ni = 0; ni < 4; ni++)
          acc[mi][ni] = mfma16(af[mi], bfr[ni], acc[mi][ni]);
    }
    __syncthreads();
  }
  #pragma unroll
  for (int mi = 0; mi < 4; mi++){
    #pragma unroll
    for (int ni = 0; ni < 4; ni++){
      #pragma unroll
      for (int r = 0; r < 4; r++){
        int m = m0 + (wr << 6) + (mi << 4) + (g << 2) + r;
        int n = n0 + (wc << 6) + (ni << 4) + c;
        if (OUTF32) ((float*)Cv)[m * N + n] = acc[mi][ni][r];
        else        ((u16*)Cv)[m * N + n] = f2bf(acc[mi][ni][r]);
      }
    }
  }
}

// ---------------- RMSNorm + RoPE; Q -> stride 96 (zeros 72..95, xlog2e), K -> stride 128 (zeros 72..127) ----------------
__global__ __launch_bounds__(192) void k_normrope(const u16* __restrict__ Y, const float* __restrict__ cosp,
      const float* __restrict__ sinp, const float* __restrict__ qnw, const float* __restrict__ knw,
      u16* __restrict__ Qp, u16* __restrict__ Kp){
  __shared__ float ly[1728];
  int token = blockIdx.x;
  int t = threadIdx.x, head = t >> 3, j = t & 7;
  int base = head * 72 + j * 9;
  const u16* yr = Y + token * 2304;
  float x[9]; float ss = 0.f;
  #pragma unroll
  for (int i = 0; i < 9; i++){ x[i] = bf2f(yr[base + i]); ss += x[i] * x[i]; }
  ss += __shfl_xor(ss, 1); ss += __shfl_xor(ss, 2); ss += __shfl_xor(ss, 4);
  float inv = rsqrtf(ss * (1.f / 72.f) + 1e-6f);
  const float* wn = (head < 16) ? qnw : knw;
  #pragma unroll
  for (int i = 0; i < 9; i++){ int d = j * 9 + i; ly[base + i] = x[i] * inv * (1.f + wn[d]); }
  __syncthreads();
  const float* cs = cosp + token * 72;
  const float* sn = sinp + token * 72;
  float scale = (head < 16) ? 1.4426950408889634f : 1.0f;
  float o[9];
  #pragma unroll
  for (int i = 0; i < 9; i++){
    int d = j * 9 + i;
    int dm = (d >= 36) ? d - 36 : d;
    float rot = (dm < 18) ? -ly[head * 72 + d + 18] : ly[head * 72 + d - 18];
    o[i] = (ly[base + i] * cs[d] + rot * sn[d]) * scale;
  }
  int b = token >> 11, s = token & 2047;
  if (head < 16){
    u16* dst = Qp + (size_t)(((b << 4) + head) * 2048 + s) * 96;
    #pragma unroll
    for (int i = 0; i < 9; i++) dst[j * 9 + i] = f2bf(o[i]);
    #pragma unroll
    for (int p2 = 0; p2 < 3; p2++) dst[72 + j * 3 + p2] = 0;
  } else {
    u16* dst = Kp + (size_t)(((b << 3) + (head - 16)) * 2048 + s) * 128;
    #pragma unroll
    for (int i = 0; i < 9; i++) dst[j * 9 + i] = f2bf(o[i]);
    #pragma unroll
    for (int p2 = 0; p2 < 7; p2++) dst[72 + j * 7 + p2] = 0;
  }
}

// ---------------- V: RMSNorm (no scale) + transpose -> Vt [4][8][72][2048] ----------------
__global__ __launch_bounds__(256) void k_vtrans(const u16* __restrict__ Y, u16* __restrict__ Vt){
  __shared__ float lv[72][33];
  int st = blockIdx.x, bk = blockIdx.y;
  int b = bk >> 3, kvh = bk & 7;
  int t = threadIdx.x, tl = t >> 3, j = t & 7;
  int token = (b << 11) + (st << 5) + tl;
  const u16* yr = Y + token * 2304 + 1728 + kvh * 72 + j * 9;
  float x[9]; float ss = 0.f;
  #pragma unroll
  for (int i = 0; i < 9; i++){ x[i] = bf2f(yr[i]); ss += x[i] * x[i]; }
  ss += __shfl_xor(ss, 1); ss += __shfl_xor(ss, 2); ss += __shfl_xor(ss, 4);
  float inv = rsqrtf(ss * (1.f / 72.f) + 1e-6f);
  #pragma unroll
  for (int i = 0; i < 9; i++) lv[j * 9 + i][tl] = x[i] * inv;
  __syncthreads();
  u16* vb = Vt + bk * 72 * 2048 + (st << 5);
  for (int e = t; e < 72 * 32; e += 256){
    int r = e >> 5, cl = e & 31;
    vb[r * 2048 + cl] = f2bf(lv[r][cl]);
  }
}

// ---------------- Flash attention: 32x32x16, KT=128, GQA head-pairing, 256-VGPR budget ----------------
// grid (32 bk, 16 qtiles of 128). 8 waves: w<4 -> head 2kv, w>=4 -> head 2kv+1; 32 q-rows/wave.
__global__ __launch_bounds__(512, 2) void k_attn(const u16* __restrict__ Qp, const u16* __restrict__ Kp,
                                                 const u16* __restrict__ Vt, u16* __restrict__ O){
  __shared__ u16 sK[2][128 * 128];  // [buf][key][16 slots of 8]; phys slot = s ^ (key&15)   64KB
  __shared__ u16 sV[2][96 * 128];   // [buf][d][16 slots of 8]; phys = s ^ (d&15); d>=72 garbage  48KB
  int tid = threadIdx.x, w = tid >> 6, lane = tid & 63, hi = lane >> 5, l31 = lane & 31;
  int bk = blockIdx.x, qt = blockIdx.y;     // all 16 qt-blocks of bk land on XCD bk&7
  int b = bk >> 3, kv = bk & 7;
  int h = (kv << 1) + (w >> 2);
  int q = (qt << 7) + ((w & 3) << 5) + l31;
  const u16* qb = Qp + (size_t)((((b << 4) + h) << 11) + q) * 96;
  s8v qf[5];
  #pragma unroll
  for (int ds = 0; ds < 5; ds++) qf[ds] = *(const s8v*)(qb + ds * 16 + hi * 8);
  f32x16 ao[3] = {};
  float mv = -3.0e38f, lsp = 0.f;
  const char* kb = (const char*)Kp + (size_t)bk * 2048 * 256;
  const char* vb = (const char*)Vt + (size_t)bk * 72 * 4096;
  // K staging: 2048 chunks of 16B; wave w takes n = (i*8+w)*64+lane, i=0..3
  int ko[4], kd[4];
  #pragma unroll
  for (int i = 0; i < 4; i++){
    int n = (i * 8 + w) * 64 + lane;
    int kr = n >> 4, sp = n & 15;
    ko[i] = kr * 256 + ((sp ^ (kr & 15)) << 4);
    kd[i] = n << 4;
  }
  // V staging: 1152 chunks (72 rows x 16); batches n, 512+n, 1024+w*16+(lane&15)
  int vo[3], vd[3];
  #pragma unroll
  for (int i = 0; i < 3; i++){
    int n = (i < 2) ? (i * 512 + w * 64 + lane) : (1024 + w * 16 + (lane & 15));
    int vr = n >> 4, sp = n & 15;
    vo[i] = vr * 4096 + ((sp ^ (vr & 15)) << 4);
    vd[i] = n << 4;
  }

#define STAGE(buf, t1) { \
    const char* kt_ = kb + (size_t)(t1) * 32768; \
    gl_lds16(kt_ + ko[0], (char*)sK[buf] + kd[0]); \
    gl_lds16(kt_ + ko[1], (char*)sK[buf] + kd[1]); \
    gl_lds16(kt_ + ko[2], (char*)sK[buf] + kd[2]); \
    gl_lds16(kt_ + ko[3], (char*)sK[buf] + kd[3]); \
    const char* vt_ = vb + (size_t)(t1) * 256; \
    gl_lds16(vt_ + vo[0], (char*)sV[buf] + vd[0]); \
    gl_lds16(vt_ + vo[1], (char*)sV[buf] + vd[1]); \
    if (lane < 16) gl_lds16(vt_ + vo[2], (char*)sV[buf] + vd[2]); }

  STAGE(0, 0)
  __syncthreads();

  #pragma unroll 1
  for (int t = 0; t < 16; t++){
    int cur = t & 1, nxt = cur ^ 1;
    if (t < 15){ STAGE(nxt, t + 1) }
    // ---- QK^T: 4 key-subtiles of 32, C[key][q] ----
    const u16* sKc = sK[cur];
    f32x16 sc[4];
    __builtin_amdgcn_s_setprio(1);
    #pragma unroll
    for (int j = 0; j < 4; j++){
      sc[j] = {};
      int r = j * 32 + l31;
      #pragma unroll
      for (int ds = 0; ds < 5; ds++){
        int s = ds * 2 + hi;
        s8v kf = *(const s8v*)(sKc + r * 128 + ((s ^ (r & 15)) << 3));
        sc[j] = mfma32(kf, qf[ds], sc[j]);
      }
    }
    __builtin_amdgcn_s_setprio(0);
    // ---- online softmax (exp2 domain): 64 scores/lane ----
    float tm = sc[0][0];
    #pragma unroll
    for (int j = 0; j < 4; j++)
      #pragma unroll
      for (int i = 0; i < 16; i++) tm = fmaxf(tm, sc[j][i]);
    tm = fmaxf(tm, __shfl_xor(tm, 32));
    if (!__all(tm <= mv + 8.f)){
      float mn = fmaxf(mv, tm);
      float scl = exp2f(mv - mn);
      lsp *= scl;
      ao[0] *= scl; ao[1] *= scl; ao[2] *= scl;
      mv = mn;
    }
    float ts0 = 0.f, ts1 = 0.f;
    #pragma unroll
    for (int j = 0; j < 4; j++){
      #pragma unroll
      for (int i = 0; i < 8; i++){ float e = exp2f(sc[j][i] - mv); sc[j][i] = e; ts0 += e; }
      #pragma unroll
      for (int i = 8; i < 16; i++){ float e = exp2f(sc[j][i] - mv); sc[j][i] = e; ts1 += e; }
    }
    lsp += ts0 + ts1;
    // ---- per-subtile: P->bf16 frags in-register, then PV ----
    const u16* sVc = sV[cur];
#define MK_PF(S, mlo, PF) { \
      u32 a0 = cvtpk(S[mlo + 0], S[mlo + 1]); \
      u32 a1 = cvtpk(S[mlo + 2], S[mlo + 3]); \
      u32 b0 = cvtpk(S[mlo + 4], S[mlo + 5]); \
      u32 b1 = cvtpk(S[mlo + 6], S[mlo + 7]); \
      asm("v_permlane32_swap_b32 %0, %1" : "+v"(a0), "+v"(b0)); \
      asm("v_permlane32_swap_b32 %0, %1" : "+v"(a1), "+v"(b1)); \
      u32x4 w4 = {a0, a1, b0, b1}; \
      PF = __builtin_bit_cast(s8v, w4); }
    #pragma unroll
    for (int j = 0; j < 4; j++){
      s8v pfa, pfb;
      MK_PF(sc[j], 0, pfa)
      MK_PF(sc[j], 8, pfb)
      __builtin_amdgcn_s_setprio(1);
      #pragma unroll
      for (int dt = 0; dt < 3; dt++){
        int r = dt * 32 + l31;
        int s0 = 4 * j + hi, s1 = 4 * j + 2 + hi;
        s8v vf0 = *(const s8v*)(sVc + r * 128 + ((s0 ^ (r & 15)) << 3));
        s8v vf1 = *(const s8v*)(sVc + r * 128 + ((s1 ^ (r & 15)) << 3));
        ao[dt] = mfma32(vf0, pfa, ao[dt]);
        ao[dt] = mfma32(vf1, pfb, ao[dt]);
      }
      __builtin_amdgcn_s_setprio(0);
    }
#undef MK_PF
    __syncthreads();
  }
  float ls = lsp + __shfl_xor(lsp, 32);
  float inv = 1.f / ls;
  u16* ob = O + (size_t)((((b << 11) + q) << 4) + h) * 72;
  #pragma unroll
  for (int dt = 0; dt < 3; dt++){
    #pragma unroll
    for (int gp = 0; gp < 4; gp++){
      int d = dt * 32 + gp * 8 + hi * 4;
      if (d < 72){
        u32x2 o2;
        o2.x = cvtpk(ao[dt][gp * 4 + 0] * inv, ao[dt][gp * 4 + 1] * inv);
        o2.y = cvtpk(ao[dt][gp * 4 + 2] * inv, ao[dt][gp * 4 + 3] * inv);
        *(u32x2*)(ob + d) = o2;
      }
    }
  }
#undef STAGE
}

// ---------------- launch ----------------
extern "C" void kernel_launch(void* const* d_in, const int* in_sizes, int n_in,
                              void* d_out, int out_size, void* d_ws, size_t ws_size,
                              hipStream_t stream){
  (void)in_sizes; (void)n_in; (void)out_size; (void)ws_size;
  const float* hs   = (const float*)d_in[0];
  const float* cosp = (const float*)d_in[1];
  const float* sinp = (const float*)d_in[2];
  const float* Wq   = (const float*)d_in[5];
  const float* Wk   = (const float*)d_in[6];
  const float* Wv   = (const float*)d_in[7];
  const float* Wo   = (const float*)d_in[8];
  const float* qnw  = (const float*)d_in[9];
  const float* knw  = (const float*)d_in[10];
  char* ws = (char*)d_ws;
  u16* Xb    = (u16*)(ws);                    // 18,874,368 B (reused as O after gemm1)
  u16* WtQKV = (u16*)(ws + 18874368);         //  5,308,416 B
  u16* Wot   = (u16*)(ws + 24182784);         //  2,654,208 B
  u16* Y     = (u16*)(ws + 26836992);         // 37,748,736 B
  u16* Qp    = (u16*)(ws + 64585728);         // 25,165,824 B (stride 96)
  u16* Kp    = (u16*)(ws + 89751552);         // 16,777,216 B (stride 128)
  u16* Vt    = (u16*)(ws + 106528768);        //  9,437,184 B  (total 115,965,952)
  u16* O     = Xb;

  k_prepx<<<4608, 256, 0, stream>>>(hs, Xb, 8192 * 1152);
  k_transpose<<<36 * 36, 256, 0, stream>>>(Wq, WtQKV, 1152, 1152, 1152);
  k_transpose<<<36 * 18, 256, 0, stream>>>(Wk, WtQKV + 1152 * 1152, 1152, 576, 1152);
  k_transpose<<<36 * 18, 256, 0, stream>>>(Wv, WtQKV + 1728 * 1152, 1152, 576, 1152);
  k_transpose<<<36 * 36, 256, 0, stream>>>(Wo, Wot, 1152, 1152, 1152);
  k_gemm<0><<<dim3(18, 64), 256, 0, stream>>>(Xb, WtQKV, Y, 8192, 2304, 1152);
  k_normrope<<<8192, 192, 0, stream>>>(Y, cosp, sinp, qnw, knw, Qp, Kp);
  k_vtrans<<<dim3(64, 32), 256, 0, stream>>>(Y, Vt);
  k_attn<<<dim3(32, 16), 512, 0, stream>>>(Qp, Kp, Vt, O);
  k_gemm<1><<<dim3(9, 64), 256, 0, stream>>>(O, Wot, (float*)d_out, 8192, 1152, 1152);
}